// Round 7
// baseline (1328.931 us; speedup 1.0000x reference)
//
#include <hip/hip_runtime.h>

#define BB 8
#define CC 64
#define HP 256
#define WP 256
#define PP 65536   // HP*WP
#define QQ 256     // 16*16
#define NBLK 1024
#define NTHR 256

// ---------- helpers ----------
__device__ __forceinline__ unsigned encF(float f) {
    unsigned u = __float_as_uint(f);
    return (u & 0x80000000u) ? ~u : (u | 0x80000000u);
}
__device__ __forceinline__ float decF(unsigned u) {
    unsigned b = (u & 0x80000000u) ? (u ^ 0x80000000u) : ~u;
    return __uint_as_float(b);
}

__device__ __forceinline__ double blockSumD(double v, double* red4) {
    int t = threadIdx.x;
    for (int d = 32; d; d >>= 1) v += __shfl_down(v, d, 64);
    __syncthreads();
    if ((t & 63) == 0) red4[t >> 6] = v;
    __syncthreads();
    double r = red4[0] + red4[1] + red4[2] + red4[3];
    __syncthreads();
    return r;
}

// grid-wide barrier: all NBLK blocks are co-resident by construction
// (__launch_bounds__(256,4) -> 4 blocks/CU x 256 CUs = 1024).
// Counter is monotonic; phase p waits for counter >= p*NBLK. Re-zeroed per
// launch by the preceding hipMemsetAsync graph node.
__device__ __forceinline__ void gsync(unsigned* bar, unsigned phase) {
    __syncthreads();
    if (threadIdx.x == 0) {
        __threadfence();
        __hip_atomic_fetch_add(bar, 1u, __ATOMIC_RELEASE, __HIP_MEMORY_SCOPE_AGENT);
        const unsigned target = phase * (unsigned)NBLK;
        while (__hip_atomic_load(bar, __ATOMIC_ACQUIRE, __HIP_MEMORY_SCOPE_AGENT) < target) {
            __builtin_amdgcn_s_sleep(4);
        }
        __threadfence();
    }
    __syncthreads();
}

__global__ __launch_bounds__(256, 4) void mega(
        const float* __restrict__ fp, const float* __restrict__ fms,
        float* __restrict__ outp, float* __restrict__ out2,
        float* __restrict__ fpm, double* __restrict__ pasumD,
        float* __restrict__ gtent, double* __restrict__ chsumD,
        double* __restrict__ chsumsqD, unsigned* __restrict__ minmax,
        int* __restrict__ histpm, int* __restrict__ msn,
        int* __restrict__ histms, int* __restrict__ histp,
        int* __restrict__ pan, float* __restrict__ hmsE,
        float* __restrict__ hjoint, float* __restrict__ naArr,
        float* __restrict__ mssum, float* __restrict__ mxArr,
        int* __restrict__ idxArr, float* __restrict__ wsel,
        int* __restrict__ chanA, int* __restrict__ minkA,
        unsigned* __restrict__ barC) {
    __shared__ __align__(16) char sm[12800];
    const int blk = blockIdx.x;
    const int tid = threadIdx.x;

    // ================= P0: zero all atomically-accumulated regions ========
    {
        int g = blk * NTHR + tid;                       // [0, 262144)
        ((float2*)fpm)[g] = make_float2(0.f, 0.f);      // 524288 floats exactly
        if (g < BB * CC * QQ) gtent[g] = 0.f;
        if (g < BB * 256) { pasumD[g] = 0.0; histpm[g] = 0; }
        if (g < BB * CC) { chsumD[g] = 0.0; chsumsqD[g] = 0.0; }
        if (g < BB * 2) minmax[g] = 0u;
    }
    gsync(barC, 1);

    // ================= P1: k3 (4096 virtual) + k4 (512 virtual) ===========
    for (int vb = blk; vb < 4608; vb += NBLK) {
        if (vb < 4096) {
            // ---- k3 body: per-(b,c,qg) 2 q-strips ----
            int qg = vb & 7, c = (vb >> 3) & 63, b = vb >> 9;
            int x = tid, s = x >> 4, r = x & 15;
            const float* src = fp + (size_t)(b * CC + c) * PP;
            float* tentL = (float*)sm;
            double* red4 = (double*)(sm + 1024);
            tentL[x] = 0.0f;
            __syncthreads();
            float wm, w0, wp;
            if (x <= 7)        { wm = 0.f; w0 = 1.f; wp = 0.f; }
            else if (x >= 248) { wm = 0.f; w0 = 1.f; wp = 0.f; }
            else if (r < 8)    { float fx = ((float)r + 8.5f) * 0.0625f; wm = 1.f - fx; w0 = fx;       wp = 0.f; }
            else               { float fx = ((float)r - 7.5f) * 0.0625f; wm = 0.f;      w0 = 1.f - fx; wp = fx;  }
            double sum = 0.0, ssq = 0.0;
#pragma unroll
            for (int qi = 0; qi < 2; ++qi) {
                int q = qg * 2 + qi;
                float am = 0.f, a0 = 0.f, ap = 0.f, cs = 0.f;
#pragma unroll
                for (int ry = 0; ry < 16; ++ry) {
                    float v = src[(q * 16 + ry) * 256 + x];
                    sum += (double)v;
                    ssq += (double)v * (double)v;
                    cs  += v;
                    if ((q == 0 && ry < 8) || (q == 15 && ry >= 8)) {
                        a0 += v;
                    } else if (ry < 8) {
                        float fy = ((float)ry + 8.5f) * 0.0625f;
                        am += (1.f - fy) * v; a0 += fy * v;
                    } else {
                        float fy = ((float)ry - 7.5f) * 0.0625f;
                        a0 += (1.f - fy) * v; ap += fy * v;
                    }
                }
                float vals[10];
                vals[0] = am * wm; vals[1] = am * w0; vals[2] = am * wp;
                vals[3] = a0 * wm; vals[4] = a0 * w0; vals[5] = a0 * wp;
                vals[6] = ap * wm; vals[7] = ap * w0; vals[8] = ap * wp;
                vals[9] = cs;
#pragma unroll
                for (int d = 8; d; d >>= 1) {
#pragma unroll
                    for (int k2 = 0; k2 < 10; ++k2) vals[k2] += __shfl_down(vals[k2], d, 16);
                }
                if (r == 0) {
                    if (q > 0) {
                        if (s > 0)  atomicAdd(&tentL[(q - 1) * 16 + (s - 1)], vals[0]);
                        atomicAdd(&tentL[(q - 1) * 16 + s], vals[1]);
                        if (s < 15) atomicAdd(&tentL[(q - 1) * 16 + (s + 1)], vals[2]);
                    }
                    if (s > 0)  atomicAdd(&tentL[q * 16 + (s - 1)], vals[3]);
                    atomicAdd(&tentL[q * 16 + s], vals[4]);
                    if (s < 15) atomicAdd(&tentL[q * 16 + (s + 1)], vals[5]);
                    if (q < 15) {
                        if (s > 0)  atomicAdd(&tentL[(q + 1) * 16 + (s - 1)], vals[6]);
                        atomicAdd(&tentL[(q + 1) * 16 + s], vals[7]);
                        if (s < 15) atomicAdd(&tentL[(q + 1) * 16 + (s + 1)], vals[8]);
                    }
                    atomicAdd(&pasumD[b * 256 + q * 16 + s], (double)vals[9]);
                }
            }
            __syncthreads();
            int row = x >> 4;
            int rlo = qg * 2 - 1; if (rlo < 0) rlo = 0;
            int rhi = qg * 2 + 2; if (rhi > 15) rhi = 15;
            if (row >= rlo && row <= rhi) {
                atomicAdd(&gtent[(size_t)(b * CC + c) * QQ + x], tentL[x]);
            }
            double st = blockSumD(sum, red4);
            double sq = blockSumD(ssq, red4);
            if (x == 0) {
                atomicAdd(&chsumD[b * CC + c], st);
                atomicAdd(&chsumsqD[b * CC + c], sq);
            }
        } else {
            // ---- k4 body: per-(b,c) f_ms stats ----
            int blk2 = vb - 4096, b = blk2 >> 6, c = blk2 & 63, t = tid;
            float* m = (float*)sm;
            int* hist = (int*)(sm + 1024);
            double* U = (double*)(sm + 2048);
            double* red4 = (double*)(sm + 4096);
            unsigned* umn = (unsigned*)(sm + 4128);
            unsigned* umx = (unsigned*)(sm + 4132);
            float v = fms[(size_t)(b * CC + c) * QQ + t];
            m[t] = v;
            hist[t] = 0;
            if (t == 0) { umn[0] = 0xFFFFFFFFu; umx[0] = 0u; }
            float mn = v, mx = v;
            for (int d = 32; d; d >>= 1) {
                mn = fminf(mn, __shfl_down(mn, d, 64));
                mx = fmaxf(mx, __shfl_down(mx, d, 64));
            }
            __syncthreads();
            if ((t & 63) == 0) { atomicMin(umn, encF(mn)); atomicMax(umx, encF(mx)); }
            __syncthreads();
            mn = decF(umn[0]); mx = decF(umx[0]);
            int bin = (int)((v - mn) / (mx - mn) * 255.0f);
            bin = min(max(bin, 0), 255);
            msn[(size_t)(b * CC + c) * QQ + t] = bin;
            atomicAdd(&hist[bin], 1);
            __syncthreads();
            histms[(size_t)(b * CC + c) * QQ + t] = hist[t];
            float pf = (float)hist[t] * (1.0f / 256.0f);
            double term = -(double)(pf * __logf(pf + 1e-8f));
            double h = blockSumD(term, red4);
            if (t == 0) hmsE[b * CC + c] = (float)h;
            int i = t >> 4, j = t & 15;
            double kdj = (j == 0 || j == 15) ? 13.328125 : 10.65625;
            double mv = (double)m[t];
            double uu = kdj * mv + 2.671875 * ((j > 0 ? (double)m[t - 1] : 0.0) +
                                               (j < 15 ? (double)m[t + 1] : 0.0));
            U[t] = uu;
            __syncthreads();
            double kdi = (i == 0 || i == 15) ? 13.328125 : 10.65625;
            double vv = kdi * U[t] + 2.671875 * ((i > 0 ? U[t - 16] : 0.0) +
                                                 (i < 15 ? U[t + 16] : 0.0));
            double sq = blockSumD(mv * vv, red4);
            double msm = blockSumD(mv, red4);
            if (t == 0) {
                mssum[b * CC + c] = (float)msm;
                double meanu = msm * (1.0 / 256.0);
                double na2 = sq - 65536.0 * meanu * meanu;
                naArr[b * CC + c] = (float)sqrt(na2 > 0.0 ? na2 : 0.0);
            }
        }
    }
    gsync(barC, 2);

    // ================= P2: kC5 f_p_a bins + histp ==========================
    if (blk < 8) {
        int b = blk, t = tid;
        int* hist = (int*)sm;
        unsigned* umn = (unsigned*)(sm + 1024);
        unsigned* umx = (unsigned*)(sm + 1028);
        hist[t] = 0;
        if (t == 0) { umn[0] = 0xFFFFFFFFu; umx[0] = 0u; }
        double acc = pasumD[b * 256 + t];
        float pa = (float)(acc * (1.0 / 256.0) * (1.0 / 64.0));
        float mn2 = pa, mx2 = pa;
        for (int d = 32; d; d >>= 1) {
            mn2 = fminf(mn2, __shfl_down(mn2, d, 64));
            mx2 = fmaxf(mx2, __shfl_down(mx2, d, 64));
        }
        __syncthreads();
        if ((t & 63) == 0) { atomicMin(umn, encF(mn2)); atomicMax(umx, encF(mx2)); }
        __syncthreads();
        mn2 = decF(umn[0]); mx2 = decF(umx[0]);
        int bin = (int)((pa - mn2) / (mx2 - mn2) * 255.0f);
        bin = min(max(bin, 0), 255);
        pan[b * QQ + t] = bin;
        atomicAdd(&hist[bin], 1);
        __syncthreads();
        histp[b * 256 + t] = hist[t];
    }
    gsync(barC, 3);

    // ================= P3: k8 (0..511) + k6 (512..1023) ====================
    {
        if (blk < 512) {
            int b = blk >> 6, c = blk & 63, t = tid;
            float* msrow = (float*)sm;
            double* part = (double*)(sm + 1024);
            double* sval = (double*)(sm + 3072);
            msrow[t] = fms[(size_t)(b * CC + c) * QQ + t];
            __syncthreads();
            int d = t >> 2, pr = t & 3;
            const float* g = gtent + (size_t)(b * CC + d) * QQ + pr * 64;
            const float* mr = msrow + pr * 64;
            double acc = 0.0;
            for (int q2 = 0; q2 < 64; ++q2) acc += (double)mr[q2] * (double)g[q2];
            part[t] = acc;
            __syncthreads();
            if (t < 64) {
                double meanu = (double)mssum[b * CC + c] * (1.0 / 256.0);
                double meanp = chsumD[b * CC + t] * (1.0 / 65536.0);
                sval[t] = part[t * 4] + part[t * 4 + 1] + part[t * 4 + 2] + part[t * 4 + 3]
                          - 65536.0 * meanu * meanp;
            }
            __syncthreads();
            if (t == 0) {
                double best = sval[0]; int bi2 = 0;
                for (int dd = 1; dd < 64; ++dd) { if (sval[dd] > best) { best = sval[dd]; bi2 = dd; } }
                double nac = (double)naArr[b * CC + c];
                double sc_ = chsumD[b * CC + c];
                double sq_ = chsumsqD[b * CC + c];
                double nb2 = sq_ - sc_ * sc_ * (1.0 / 65536.0);
                double nbc = sqrt(nb2 > 0.0 ? nb2 : 0.0);
                mxArr[b * CC + c] = (float)(best * 100.0 / (nac * nbc));
                idxArr[b * CC + c] = bi2;
            }
        } else {
            int vb = blk - 512, b = vb >> 6, c = vb & 63, t = tid;
            int* key = (int*)sm;
            int* hms = (int*)(sm + 1024);
            int* hp = (int*)(sm + 2048);
            double* red4 = (double*)(sm + 3072);
            int iv = msn[(size_t)(b * CC + c) * QQ + t];
            int jv = pan[b * QQ + t];
            key[t] = (iv << 8) | jv;
            hms[t] = histms[(size_t)(b * CC + c) * QQ + t];
            hp[t] = histp[b * 256 + t];
            __syncthreads();
            unsigned long long w0_ = 0, w1_ = 0, w2_ = 0, w3_ = 0;
            for (int p = 0; p < 256; ++p) {
                int k2 = key[p];
                if ((k2 >> 8) == t) {
                    int j = k2 & 255;
                    unsigned long long bit = 1ull << (j & 63);
                    int w = j >> 6;
                    if (w == 0) w0_ |= bit; else if (w == 1) w1_ |= bit;
                    else if (w == 2) w2_ |= bit; else w3_ |= bit;
                }
            }
            double acc = 0.0;
            int basei = 256 - hms[t];
            unsigned long long words[4] = { w0_, w1_, w2_, w3_ };
#pragma unroll
            for (int w = 0; w < 4; ++w) {
                unsigned long long word = words[w];
                for (int jj = 0; jj < 64; ++jj) {
                    if (!((word >> jj) & 1ull)) {
                        int cnt = basei - hp[w * 64 + jj];
                        float pf = (float)cnt * (1.0f / 65536.0f);
                        acc -= (double)(pf * __logf(pf + 1e-8f));
                    }
                }
            }
            int myk = key[t], n = 0; bool first = true;
            for (int p = 0; p < 256; ++p) {
                int k2 = key[p];
                if (k2 == myk) { n++; if (p < t) first = false; }
            }
            if (first) {
                int cnt = 2 * n + 256 - hms[myk >> 8] - hp[myk & 255];
                float pf = (float)cnt * (1.0f / 65536.0f);
                acc -= (double)(pf * __logf(pf + 1e-8f));
            }
            double h = blockSumD(acc, red4);
            if (t == 0) hjoint[b * CC + c] = (float)h;
        }
    }
    gsync(barC, 4);

    // ================= P4: k9 on block 0 (256 thr, 2 batches per wave) =====
    if (blk == 0) {
        double* sc = (double*)sm;              // [8][64]
        double* gs = (double*)(sm + 4096);     // [8][64]
        int* idxS = (int*)(sm + 8192);         // [8][64]
        int* ordv = (int*)(sm + 10240);        // [8][64]
        int* uarr = (int*)(sm + 12288);        // [8]
        int* mkS  = (int*)(sm + 12320);
        int t = tid, c = t & 63, wv = t >> 6;
#pragma unroll
        for (int pass = 0; pass < 2; ++pass) {
            int b = wv + pass * 4;
            double v = (double)mxArr[b * 64 + c];
            double mx = v;
            for (int d = 32; d; d >>= 1) mx = fmax(mx, __shfl_down(mx, d, 64));
            mx = __shfl(mx, 0, 64);
            double e = exp(v - mx);
            double s = e;
            for (int d = 32; d; d >>= 1) s += __shfl_down(s, d, 64);
            s = __shfl(s, 0, 64);
            sc[b * 64 + c] = e / s;
            idxS[b * 64 + c] = idxArr[b * 64 + c];
        }
        __syncthreads();
#pragma unroll
        for (int pass = 0; pass < 2; ++pass) {
            int b = wv + pass * 4;
            double g = 0.0; int cnt = 0;
            for (int c2 = 0; c2 < 64; ++c2) {
                if (idxS[b * 64 + c2] == c) { g += sc[b * 64 + c2]; cnt++; }
            }
            gs[b * 64 + c] = g;
            unsigned long long ball = __ballot(cnt > 0);
            if (c == 0) uarr[b] = __popcll(ball);
        }
        __syncthreads();
        if (t == 0) {
            int k = uarr[0];
            for (int b2 = 1; b2 < 8; ++b2) k = min(k, uarr[b2]);
            mkS[0] = (k + 1) >> 1;
            minkA[0] = mkS[0];
        }
        __syncthreads();
#pragma unroll
        for (int pass = 0; pass < 2; ++pass) {
            int b = wv + pass * 4;
            int rk = 0;
            double myg = gs[b * 64 + c];
            for (int c3 = 0; c3 < 64; ++c3) {
                double a = gs[b * 64 + c3];
                if (a > myg || (a == myg && c3 < c)) rk++;
            }
            ordv[b * 64 + rk] = c;
        }
        __syncthreads();
#pragma unroll
        for (int pass = 0; pass < 2; ++pass) {
            int b = wv + pass * 4;
            int mk = mkS[0];
            double z0 = gs[b * 64 + ordv[b * 64 + 0]];
            double ee = (c < mk) ? exp(gs[b * 64 + ordv[b * 64 + c]] - z0) : 0.0;
            double se = ee;
            for (int d = 32; d; d >>= 1) se += __shfl_down(se, d, 64);
            se = __shfl(se, 0, 64);
            if (c < mk) {
                wsel[b * 64 + c] = (float)(ee / se);
                chanA[b * 64 + c] = ordv[b * 64 + c];
            }
        }
    }
    gsync(barC, 5);

    // ================= P5a: rel_p stream, split in channel halves ==========
    {
        int half = blk >> 9;               // 0 or 1
        int b = (blk >> 6) & 7;
        int ih = blk & 63;
        int i4 = ih * 256 + tid;
        int mk = minkA[0];
        const float4* src = (const float4*)(fp + (size_t)b * CC * PP);
        float mx0 = 0.f, mx1 = 0.f, mx2 = 0.f, mx3 = 0.f;
        for (int i = 0; i < mk; ++i) {
            int ch = chanA[b * 64 + i];
            float wv = wsel[b * 64 + i];
            float4 v = src[(size_t)ch * (PP / 4) + i4];
            mx0 += wv * (1.0f / (1.0f + __expf(-v.x)));
            mx1 += wv * (1.0f / (1.0f + __expf(-v.y)));
            mx2 += wv * (1.0f / (1.0f + __expf(-v.z)));
            mx3 += wv * (1.0f / (1.0f + __expf(-v.w)));
        }
        float sx = 0.f, sy = 0.f, sz = 0.f, sw = 0.f;
        float4* dst = (float4*)(outp + (size_t)b * CC * PP);
        int c0 = half * 32;
        for (int c2 = c0; c2 < c0 + 32; ++c2) {
            float4 v = src[(size_t)c2 * (PP / 4) + i4];
            sx += v.x; sy += v.y; sz += v.z; sw += v.w;
            float4 o;
            o.x = v.x + v.x * mx0;
            o.y = v.y + v.y * mx1;
            o.z = v.z + v.z * mx2;
            o.w = v.w + v.w * mx3;
            dst[(size_t)c2 * (PP / 4) + i4] = o;
        }
        // raw channel-sum partials (binning is scale-invariant; /64 exact anyway)
        float* fb = fpm + (size_t)b * PP + (size_t)i4 * 4;
        atomicAdd(&fb[0], sx); atomicAdd(&fb[1], sy);
        atomicAdd(&fb[2], sz); atomicAdd(&fb[3], sw);
    }
    gsync(barC, 6);

    // ================= P5b: per-b min/max of raw channel sums ==============
    if (blk < 512) {
        int b = blk >> 6;
        int i4 = (blk & 63) * 256 + tid;
        unsigned* smn = (unsigned*)sm;
        unsigned* smx = (unsigned*)(sm + 4);
        float4 m = ((const float4*)(fpm + (size_t)b * PP))[i4];
        float mn = fminf(fminf(m.x, m.y), fminf(m.z, m.w));
        float mxv = fmaxf(fmaxf(m.x, m.y), fmaxf(m.z, m.w));
        for (int d = 32; d; d >>= 1) {
            mn = fminf(mn, __shfl_down(mn, d, 64));
            mxv = fmaxf(mxv, __shfl_down(mxv, d, 64));
        }
        if (tid == 0) { smn[0] = 0u; smx[0] = 0u; }
        __syncthreads();
        if ((tid & 63) == 0) { atomicMax(smn, ~encF(mn)); atomicMax(smx, encF(mxv)); }
        __syncthreads();
        if (tid == 0) { atomicMax(&minmax[2 * b], smn[0]); atomicMax(&minmax[2 * b + 1], smx[0]); }
    }
    gsync(barC, 7);

    // ================= P6: histogram of norm255(f_p_m) =====================
    if (blk < 512) {
        int b = blk >> 6;
        int* h = (int*)sm;
        h[tid] = 0;
        __syncthreads();
        float mn = decF(~minmax[2 * b]);
        float mx = decF(minmax[2 * b + 1]);
        float dd = mx - mn;
        int i4 = (blk & 63) * 256 + tid;
        float4 v = ((const float4*)(fpm + (size_t)b * PP))[i4];
        int b0 = (int)((v.x - mn) / dd * 255.0f);
        int b1 = (int)((v.y - mn) / dd * 255.0f);
        int b2 = (int)((v.z - mn) / dd * 255.0f);
        int b3 = (int)((v.w - mn) / dd * 255.0f);
        b0 = min(max(b0, 0), 255); b1 = min(max(b1, 0), 255);
        b2 = min(max(b2, 0), 255); b3 = min(max(b3, 0), 255);
        atomicAdd(&h[b0], 1); atomicAdd(&h[b1], 1);
        atomicAdd(&h[b2], 1); atomicAdd(&h[b3], 1);
        __syncthreads();
        atomicAdd(&histpm[b * 256 + tid], h[tid]);
    }
    gsync(barC, 8);

    // ================= P7: entropy + mi softmax + rel_ms ===================
    if (blk < 8) {
        int b = blk, t = tid;
        double* red4 = (double*)sm;
        double* mi = (double*)(sm + 32);
        float* hpEs = (float*)(sm + 544);
        int n = histpm[b * 256 + t];
        float p = (float)n * (1.0f / 65536.0f);
        double term = -(double)(p * __logf(p + 1e-8f));
        double h = blockSumD(term, red4);
        if (t == 0) hpEs[0] = (float)h;
        __syncthreads();
        if (t < 64) mi[t] = (double)hpEs[0] + (double)hmsE[b * CC + t] - (double)hjoint[b * CC + t];
        __syncthreads();
        if (t == 0) {
            double mxv = mi[0];
            for (int c2 = 1; c2 < 64; ++c2) if (mi[c2] > mxv) mxv = mi[c2];
            double s = 0.0;
            for (int c2 = 0; c2 < 64; ++c2) { mi[c2] = exp(mi[c2] - mxv); s += mi[c2]; }
            for (int c2 = 0; c2 < 64; ++c2) mi[c2] /= s;
        }
        __syncthreads();
        const float* srcm = fms + (size_t)b * CC * QQ;
        float* dstm = out2 + (size_t)b * CC * QQ;
        for (int e = t; e < CC * QQ; e += 256) {
            float v = srcm[e];
            float miv = (float)mi[e >> 8];
            dstm[e] = v + v * miv;
        }
    }
}

extern "C" void kernel_launch(void* const* d_in, const int* in_sizes, int n_in,
                              void* d_out, int out_size, void* d_ws, size_t ws_size,
                              hipStream_t stream) {
    const float* fp = (const float*)d_in[0];   // [8,64,256,256]
    const float* fms = (const float*)d_in[1];  // [8,64,16,16]
    float* out = (float*)d_out;

    char* p = (char*)d_ws;
    auto alloc = [&](size_t bytes) { void* r = (void*)p; p += (bytes + 255) & ~(size_t)255; return r; };

    float* fpm      = (float*)alloc((size_t)BB * PP * 4);        // 2 MB (raw channel sums)
    float* gtent    = (float*)alloc((size_t)BB * CC * QQ * 4);   // 512 KB
    double* pasumD  = (double*)alloc((size_t)BB * 256 * 8);
    double* chsumD  = (double*)alloc((size_t)BB * CC * 8);
    double* chsumsqD= (double*)alloc((size_t)BB * CC * 8);
    unsigned* minmax= (unsigned*)alloc((size_t)BB * 2 * 4);
    int* histpm     = (int*)alloc((size_t)BB * 256 * 4);
    int* msn        = (int*)alloc((size_t)BB * CC * QQ * 4);     // 512 KB
    int* histms     = (int*)alloc((size_t)BB * CC * 256 * 4);    // 512 KB
    int* histp      = (int*)alloc((size_t)BB * 256 * 4);
    int* pan        = (int*)alloc((size_t)BB * QQ * 4);
    float* hmsE     = (float*)alloc((size_t)BB * CC * 4);
    float* hjoint   = (float*)alloc((size_t)BB * CC * 4);
    float* naArr    = (float*)alloc((size_t)BB * CC * 4);
    float* mssum    = (float*)alloc((size_t)BB * CC * 4);
    float* mxArr    = (float*)alloc((size_t)BB * CC * 4);
    int* idxArr     = (int*)alloc((size_t)BB * CC * 4);
    float* wsel     = (float*)alloc((size_t)BB * CC * 4);
    int* chanA      = (int*)alloc((size_t)BB * CC * 4);
    int* minkA      = (int*)alloc(256);
    unsigned* barC  = (unsigned*)alloc(256);

    float* out_relp  = out;                                      // [8,64,256,256]
    float* out_relms = out + (size_t)BB * CC * PP;               // [8,64,16,16]

    hipMemsetAsync(barC, 0, 256, stream);   // re-zero barrier counter per replay
    mega<<<NBLK, NTHR, 0, stream>>>(fp, fms, out_relp, out_relms,
                                    fpm, pasumD, gtent, chsumD, chsumsqD,
                                    minmax, histpm, msn, histms, histp, pan,
                                    hmsE, hjoint, naArr, mssum, mxArr, idxArr,
                                    wsel, chanA, minkA, barC);
}

// Round 8
// 383.206 us; speedup vs baseline: 3.4679x; 3.4679x over previous
//
#include <hip/hip_runtime.h>

#define BB 8
#define CC 64
#define HP 256
#define WP 256
#define PP 65536   // HP*WP
#define QQ 256     // 16*16

// ---------- helpers ----------
__device__ __forceinline__ unsigned encF(float f) {
    unsigned u = __float_as_uint(f);
    return (u & 0x80000000u) ? ~u : (u | 0x80000000u);
}
__device__ __forceinline__ float decF(unsigned u) {
    unsigned b = (u & 0x80000000u) ? (u ^ 0x80000000u) : ~u;
    return __uint_as_float(b);
}

// block of 256 threads, sum of doubles; red4 is __shared__ double[4]
__device__ __forceinline__ double blockSumD(double v, double* red4) {
    int t = threadIdx.x;
    for (int d = 32; d; d >>= 1) v += __shfl_down(v, d, 64);
    __syncthreads();
    if ((t & 63) == 0) red4[t >> 6] = v;
    __syncthreads();
    double r = red4[0] + red4[1] + red4[2] + red4[3];
    __syncthreads();
    return r;
}

// ---------- L1: k3 (4096 blocks, 2 q-strips each) + k4 (512 blocks) ----------
__global__ __launch_bounds__(256) void k34_fused(const float* __restrict__ fp,
                                                 const float* __restrict__ fms,
                                                 double* __restrict__ pasumD,
                                                 float* __restrict__ gtent,
                                                 double* __restrict__ chsumD,
                                                 double* __restrict__ chsumsqD,
                                                 int* __restrict__ msn,
                                                 int* __restrict__ histms,
                                                 float* __restrict__ hmsE,
                                                 float* __restrict__ naArr,
                                                 float* __restrict__ mssum) {
    int blk = blockIdx.x;
    if (blk < 4096) {
        // ---- k3 body: per-(b,c,qg) 2 q-strips ----
        int qg = blk & 7, c = (blk >> 3) & 63, b = blk >> 9;
        int x = threadIdx.x, s = x >> 4, r = x & 15;
        const float* src = fp + (size_t)(b * CC + c) * PP;
        __shared__ float tentL[256];
        __shared__ double red4[4];
        tentL[x] = 0.0f;
        __syncthreads();
        float wm, w0, wp;
        if (x <= 7)        { wm = 0.f; w0 = 1.f; wp = 0.f; }
        else if (x >= 248) { wm = 0.f; w0 = 1.f; wp = 0.f; }
        else if (r < 8)    { float fx = ((float)r + 8.5f) * 0.0625f; wm = 1.f - fx; w0 = fx;       wp = 0.f; }
        else               { float fx = ((float)r - 7.5f) * 0.0625f; wm = 0.f;      w0 = 1.f - fx; wp = fx;  }
        double sum = 0.0, ssq = 0.0;
#pragma unroll
        for (int qi = 0; qi < 2; ++qi) {
            int q = qg * 2 + qi;
            float am = 0.f, a0 = 0.f, ap = 0.f, cs = 0.f;
#pragma unroll
            for (int ry = 0; ry < 16; ++ry) {
                float v = src[(q * 16 + ry) * 256 + x];
                sum += (double)v;
                ssq += (double)v * (double)v;
                cs  += v;
                if ((q == 0 && ry < 8) || (q == 15 && ry >= 8)) {
                    a0 += v;
                } else if (ry < 8) {
                    float fy = ((float)ry + 8.5f) * 0.0625f;
                    am += (1.f - fy) * v; a0 += fy * v;
                } else {
                    float fy = ((float)ry - 7.5f) * 0.0625f;
                    a0 += (1.f - fy) * v; ap += fy * v;
                }
            }
            float vals[10];
            vals[0] = am * wm; vals[1] = am * w0; vals[2] = am * wp;
            vals[3] = a0 * wm; vals[4] = a0 * w0; vals[5] = a0 * wp;
            vals[6] = ap * wm; vals[7] = ap * w0; vals[8] = ap * wp;
            vals[9] = cs;
#pragma unroll
            for (int d = 8; d; d >>= 1) {
#pragma unroll
                for (int k2 = 0; k2 < 10; ++k2) vals[k2] += __shfl_down(vals[k2], d, 16);
            }
            if (r == 0) {
                if (q > 0) {
                    if (s > 0)  atomicAdd(&tentL[(q - 1) * 16 + (s - 1)], vals[0]);
                    atomicAdd(&tentL[(q - 1) * 16 + s], vals[1]);
                    if (s < 15) atomicAdd(&tentL[(q - 1) * 16 + (s + 1)], vals[2]);
                }
                if (s > 0)  atomicAdd(&tentL[q * 16 + (s - 1)], vals[3]);
                atomicAdd(&tentL[q * 16 + s], vals[4]);
                if (s < 15) atomicAdd(&tentL[q * 16 + (s + 1)], vals[5]);
                if (q < 15) {
                    if (s > 0)  atomicAdd(&tentL[(q + 1) * 16 + (s - 1)], vals[6]);
                    atomicAdd(&tentL[(q + 1) * 16 + s], vals[7]);
                    if (s < 15) atomicAdd(&tentL[(q + 1) * 16 + (s + 1)], vals[8]);
                }
                atomicAdd(&pasumD[b * 256 + q * 16 + s], (double)vals[9]);
            }
        }
        __syncthreads();
        // flush only the tent rows this block can have touched: [2qg-1, 2qg+2]
        int row = x >> 4;
        int rlo = qg * 2 - 1; if (rlo < 0) rlo = 0;
        int rhi = qg * 2 + 2; if (rhi > 15) rhi = 15;
        if (row >= rlo && row <= rhi) {
            atomicAdd(&gtent[(size_t)(b * CC + c) * QQ + x], tentL[x]);
        }
        double st = blockSumD(sum, red4);
        double sq = blockSumD(ssq, red4);
        if (x == 0) {
            atomicAdd(&chsumD[b * CC + c], st);
            atomicAdd(&chsumsqD[b * CC + c], sq);
        }
    } else {
        // ---- k4 body: per-(b,c) f_ms stats ----
        int blk2 = blk - 4096, b = blk2 >> 6, c = blk2 & 63, t = threadIdx.x;
        __shared__ float m[256];
        __shared__ int hist[256];
        __shared__ double red4[4];
        __shared__ double U[256];
        __shared__ unsigned umn, umx;
        float v = fms[(size_t)(b * CC + c) * QQ + t];
        m[t] = v;
        hist[t] = 0;
        if (t == 0) { umn = 0xFFFFFFFFu; umx = 0u; }
        float mn = v, mx = v;
        for (int d = 32; d; d >>= 1) {
            mn = fminf(mn, __shfl_down(mn, d, 64));
            mx = fmaxf(mx, __shfl_down(mx, d, 64));
        }
        __syncthreads();
        if ((t & 63) == 0) { atomicMin(&umn, encF(mn)); atomicMax(&umx, encF(mx)); }
        __syncthreads();
        mn = decF(umn); mx = decF(umx);
        int bin = (int)((v - mn) / (mx - mn) * 255.0f);
        bin = min(max(bin, 0), 255);
        msn[(size_t)(b * CC + c) * QQ + t] = bin;
        atomicAdd(&hist[bin], 1);
        __syncthreads();
        histms[(size_t)(b * CC + c) * QQ + t] = hist[t];
        float pf = (float)hist[t] * (1.0f / 256.0f);
        double term = -(double)(pf * __logf(pf + 1e-8f));
        double h = blockSumD(term, red4);
        if (t == 0) hmsE[b * CC + c] = (float)h;
        int i = t >> 4, j = t & 15;
        double kdj = (j == 0 || j == 15) ? 13.328125 : 10.65625;
        double mv = (double)m[t];
        double uu = kdj * mv + 2.671875 * ((j > 0 ? (double)m[t - 1] : 0.0) +
                                           (j < 15 ? (double)m[t + 1] : 0.0));
        U[t] = uu;
        __syncthreads();
        double kdi = (i == 0 || i == 15) ? 13.328125 : 10.65625;
        double vv = kdi * U[t] + 2.671875 * ((i > 0 ? U[t - 16] : 0.0) +
                                             (i < 15 ? U[t + 16] : 0.0));
        double sq = blockSumD(mv * vv, red4);
        double msm = blockSumD(mv, red4);
        if (t == 0) {
            mssum[b * CC + c] = (float)msm;
            double meanu = msm * (1.0 / 256.0);
            double na2 = sq - 65536.0 * meanu * meanu;
            naArr[b * CC + c] = (float)sqrt(na2 > 0.0 ? na2 : 0.0);
        }
    }
}

// ---------- L2: f_p_a bins + histp from pasumD (one f64 load per thread) ----------
__global__ __launch_bounds__(256) void kC5_pa(const double* __restrict__ pasumD,
                                              int* __restrict__ pan,
                                              int* __restrict__ histp) {
    int b = blockIdx.x, t = threadIdx.x;
    __shared__ int hist[256];
    __shared__ unsigned umn, umx;
    hist[t] = 0;
    if (t == 0) { umn = 0xFFFFFFFFu; umx = 0u; }
    double acc = pasumD[b * 256 + t];
    float pa = (float)(acc * (1.0 / 256.0) * (1.0 / 64.0));
    float mn2 = pa, mx2 = pa;
    for (int d = 32; d; d >>= 1) {
        mn2 = fminf(mn2, __shfl_down(mn2, d, 64));
        mx2 = fmaxf(mx2, __shfl_down(mx2, d, 64));
    }
    __syncthreads();
    if ((t & 63) == 0) { atomicMin(&umn, encF(mn2)); atomicMax(&umx, encF(mx2)); }
    __syncthreads();
    mn2 = decF(umn); mx2 = decF(umx);
    int bin = (int)((pa - mn2) / (mx2 - mn2) * 255.0f);
    bin = min(max(bin, 0), 255);
    pan[b * QQ + t] = bin;
    atomicAdd(&hist[bin], 1);
    __syncthreads();
    histp[b * 256 + t] = hist[t];
}

// ---------- L3: k8 (blocks 0..511) + k6 joint entropy (blocks 512..1023) ----------
__global__ __launch_bounds__(256) void k86_fused(const float* __restrict__ fms,
                                                 const float* __restrict__ gtent,
                                                 const float* __restrict__ mssum,
                                                 const double* __restrict__ chsumD,
                                                 const double* __restrict__ chsumsqD,
                                                 const float* __restrict__ naArr,
                                                 const int* __restrict__ msn,
                                                 const int* __restrict__ pan,
                                                 const int* __restrict__ histms,
                                                 const int* __restrict__ histp,
                                                 float* __restrict__ mxArr,
                                                 int* __restrict__ idxArr,
                                                 float* __restrict__ hjoint) {
    int blk0 = blockIdx.x;
    if (blk0 < 512) {
        // ---- k8 body ----
        int blk = blk0, b = blk >> 6, c = blk & 63, t = threadIdx.x;
        __shared__ float msrow[256];
        __shared__ double part[256];
        __shared__ double sval[64];
        msrow[t] = fms[(size_t)(b * CC + c) * QQ + t];
        __syncthreads();
        int d = t >> 2, pr = t & 3;
        const float* g = gtent + (size_t)(b * CC + d) * QQ + pr * 64;
        const float* mr = msrow + pr * 64;
        double acc = 0.0;
        for (int q2 = 0; q2 < 64; ++q2) acc += (double)mr[q2] * (double)g[q2];
        part[t] = acc;
        __syncthreads();
        if (t < 64) {
            double meanu = (double)mssum[b * CC + c] * (1.0 / 256.0);
            double meanp = chsumD[b * CC + t] * (1.0 / 65536.0);
            sval[t] = part[t * 4] + part[t * 4 + 1] + part[t * 4 + 2] + part[t * 4 + 3]
                      - 65536.0 * meanu * meanp;
        }
        __syncthreads();
        if (t == 0) {
            double best = sval[0]; int bi2 = 0;
            for (int dd = 1; dd < 64; ++dd) { if (sval[dd] > best) { best = sval[dd]; bi2 = dd; } }
            double nac = (double)naArr[b * CC + c];
            double sc_ = chsumD[b * CC + c];
            double sq_ = chsumsqD[b * CC + c];
            double nb2 = sq_ - sc_ * sc_ * (1.0 / 65536.0);
            double nbc = sqrt(nb2 > 0.0 ? nb2 : 0.0);
            mxArr[b * CC + c] = (float)(best * 100.0 / (nac * nbc));
            idxArr[b * CC + c] = bi2;
        }
    } else {
        // ---- k6 body ----
        int blk = blk0 - 512, b = blk >> 6, c = blk & 63, t = threadIdx.x;
        __shared__ int key[256], hms[256], hp[256];
        __shared__ double red4[4];
        int iv = msn[(size_t)(b * CC + c) * QQ + t];
        int jv = pan[b * QQ + t];
        key[t] = (iv << 8) | jv;
        hms[t] = histms[(size_t)(b * CC + c) * QQ + t];
        hp[t] = histp[b * 256 + t];
        __syncthreads();
        unsigned long long w0_ = 0, w1_ = 0, w2_ = 0, w3_ = 0;
        for (int p = 0; p < 256; ++p) {
            int k2 = key[p];
            if ((k2 >> 8) == t) {
                int j = k2 & 255;
                unsigned long long bit = 1ull << (j & 63);
                int w = j >> 6;
                if (w == 0) w0_ |= bit; else if (w == 1) w1_ |= bit;
                else if (w == 2) w2_ |= bit; else w3_ |= bit;
            }
        }
        double acc = 0.0;
        int basei = 256 - hms[t];
        unsigned long long words[4] = { w0_, w1_, w2_, w3_ };
#pragma unroll
        for (int w = 0; w < 4; ++w) {
            unsigned long long word = words[w];
            for (int jj = 0; jj < 64; ++jj) {
                if (!((word >> jj) & 1ull)) {
                    int cnt = basei - hp[w * 64 + jj];
                    float pf = (float)cnt * (1.0f / 65536.0f);
                    acc -= (double)(pf * __logf(pf + 1e-8f));
                }
            }
        }
        int myk = key[t], n = 0; bool first = true;
        for (int p = 0; p < 256; ++p) {
            int k2 = key[p];
            if (k2 == myk) { n++; if (p < t) first = false; }
        }
        if (first) {
            int cnt = 2 * n + 256 - hms[myk >> 8] - hp[myk & 255];
            float pf = (float)cnt * (1.0f / 65536.0f);
            acc -= (double)(pf * __logf(pf + 1e-8f));
        }
        double h = blockSumD(acc, red4);
        if (t == 0) hjoint[b * CC + c] = (float)h;
    }
}

// ---------- L4: K9 scores, grouping, min_k, stable sort, selection weights ----------
__global__ __launch_bounds__(512) void k9_small(const float* __restrict__ mxArr,
                                                const int* __restrict__ idxArr,
                                                float* __restrict__ wsel,
                                                int* __restrict__ chanA,
                                                int* __restrict__ minkA) {
    __shared__ double sc[8][64];
    __shared__ double gs[8][64];
    __shared__ int idxS[8][64];
    __shared__ int ordv[8][64];
    __shared__ int uarr[8];
    __shared__ int mkS;
    int t = threadIdx.x;
    int b = t >> 6, c = t & 63;
    double v = (double)mxArr[b * 64 + c];
    double mx = v;
    for (int d = 32; d; d >>= 1) mx = fmax(mx, __shfl_down(mx, d, 64));
    mx = __shfl(mx, 0, 64);
    double e = exp(v - mx);
    double s = e;
    for (int d = 32; d; d >>= 1) s += __shfl_down(s, d, 64);
    s = __shfl(s, 0, 64);
    sc[b][c] = e / s;
    idxS[b][c] = idxArr[b * 64 + c];
    __syncthreads();
    double g = 0.0; int cnt = 0;
    for (int c2 = 0; c2 < 64; ++c2) {
        if (idxS[b][c2] == c) { g += sc[b][c2]; cnt++; }
    }
    gs[b][c] = g;
    unsigned long long ball = __ballot(cnt > 0);
    if (c == 0) uarr[b] = __popcll(ball);
    __syncthreads();
    if (t == 0) {
        int k = uarr[0];
        for (int b2 = 1; b2 < 8; ++b2) k = min(k, uarr[b2]);
        mkS = (k + 1) >> 1;
        minkA[0] = mkS;
    }
    __syncthreads();
    int rk = 0;
    double myg = gs[b][c];
    for (int c3 = 0; c3 < 64; ++c3) {
        double a = gs[b][c3];
        if (a > myg || (a == myg && c3 < c)) rk++;
    }
    ordv[b][rk] = c;
    __syncthreads();
    int mk = mkS;
    double z0 = gs[b][ordv[b][0]];
    double ee = (c < mk) ? exp(gs[b][ordv[b][c]] - z0) : 0.0;
    double se = ee;
    for (int d = 32; d; d >>= 1) se += __shfl_down(se, d, 64);
    se = __shfl(se, 0, 64);
    if (c < mk) {
        wsel[b * 64 + c] = (float)(ee / se);
        chanA[b * 64 + c] = ordv[b][c];
    }
}

// ---------- L5: rel_p = f_p*(1+mask) with fused mask prologue + f_p_m + minmax ----------
// minmax encoding: BOTH entries are atomicMax-accumulated with 0-init:
//   minmax[2b]   = max(~encF(v))  -> min = decF(~minmax[2b])
//   minmax[2b+1] = max( encF(v))  -> max = decF(minmax[2b+1])
__global__ __launch_bounds__(256) void k10_relp(const float* __restrict__ fp,
                                                const float* __restrict__ wsel,
                                                const int* __restrict__ chanA,
                                                const int* __restrict__ minkA,
                                                float* __restrict__ outp,
                                                float* __restrict__ fpm,
                                                unsigned* __restrict__ minmax) {
    int b = blockIdx.y;
    int i4 = blockIdx.x * 256 + threadIdx.x;
    int mk = minkA[0];
    const float4* src = (const float4*)(fp + (size_t)b * CC * PP);
    // ---- mask prologue (was kM) ----
    float mx0 = 0.f, mx1 = 0.f, mx2 = 0.f, mx3 = 0.f;
    for (int i = 0; i < mk; ++i) {
        int ch = chanA[b * 64 + i];
        float wv = wsel[b * 64 + i];
        float4 v = src[(size_t)ch * (PP / 4) + i4];
        mx0 += wv * (1.0f / (1.0f + __expf(-v.x)));
        mx1 += wv * (1.0f / (1.0f + __expf(-v.y)));
        mx2 += wv * (1.0f / (1.0f + __expf(-v.z)));
        mx3 += wv * (1.0f / (1.0f + __expf(-v.w)));
    }
    // ---- stream all 64 channels: write rel_p, accumulate channel mean ----
    float sx = 0.f, sy = 0.f, sz = 0.f, sw = 0.f;
    float4* dst = (float4*)(outp + (size_t)b * CC * PP);
    for (int c2 = 0; c2 < CC; ++c2) {
        float4 v = src[(size_t)c2 * (PP / 4) + i4];
        sx += v.x; sy += v.y; sz += v.z; sw += v.w;
        float4 o;
        o.x = v.x + v.x * mx0;
        o.y = v.y + v.y * mx1;
        o.z = v.z + v.z * mx2;
        o.w = v.w + v.w * mx3;
        dst[(size_t)c2 * (PP / 4) + i4] = o;
    }
    const float inv = 1.0f / 64.0f;
    float4 m; m.x = sx * inv; m.y = sy * inv; m.z = sz * inv; m.w = sw * inv;
    ((float4*)(fpm + (size_t)b * PP))[i4] = m;
    float mn = fminf(fminf(m.x, m.y), fminf(m.z, m.w));
    float mxv = fmaxf(fmaxf(m.x, m.y), fmaxf(m.z, m.w));
    for (int d = 32; d; d >>= 1) {
        mn = fminf(mn, __shfl_down(mn, d, 64));
        mxv = fmaxf(mxv, __shfl_down(mxv, d, 64));
    }
    __shared__ unsigned smn, smx;
    if (threadIdx.x == 0) { smn = 0u; smx = 0u; }
    __syncthreads();
    if ((threadIdx.x & 63) == 0) { atomicMax(&smn, ~encF(mn)); atomicMax(&smx, encF(mxv)); }
    __syncthreads();
    if (threadIdx.x == 0) { atomicMax(&minmax[2 * b], smn); atomicMax(&minmax[2 * b + 1], smx); }
}

// ---------- L6: parallel histogram of norm255(f_p_m) ----------
__global__ __launch_bounds__(256) void k2a_hist(const float* __restrict__ fpm,
                                                const unsigned* __restrict__ minmax,
                                                int* __restrict__ histpm) {
    int b = blockIdx.y;
    __shared__ int h[256];
    h[threadIdx.x] = 0;
    __syncthreads();
    float mn = decF(~minmax[2 * b]);
    float mx = decF(minmax[2 * b + 1]);
    float dd = mx - mn;
    int i4 = blockIdx.x * 256 + threadIdx.x;
    float4 v = ((const float4*)(fpm + (size_t)b * PP))[i4];
    int b0 = (int)((v.x - mn) / dd * 255.0f);
    int b1 = (int)((v.y - mn) / dd * 255.0f);
    int b2 = (int)((v.z - mn) / dd * 255.0f);
    int b3 = (int)((v.w - mn) / dd * 255.0f);
    b0 = min(max(b0, 0), 255); b1 = min(max(b1, 0), 255);
    b2 = min(max(b2, 0), 255); b3 = min(max(b3, 0), 255);
    atomicAdd(&h[b0], 1); atomicAdd(&h[b1], 1);
    atomicAdd(&h[b2], 1); atomicAdd(&h[b3], 1);
    __syncthreads();
    atomicAdd(&histpm[b * 256 + threadIdx.x], h[threadIdx.x]);
}

// ---------- L7: entropy(histpm) + mi softmax + rel_ms, one block per b ----------
__global__ __launch_bounds__(256) void kF_relms(const int* __restrict__ histpm,
                                                const float* __restrict__ fms,
                                                const float* __restrict__ hmsE,
                                                const float* __restrict__ hjoint,
                                                float* __restrict__ out2) {
    int b = blockIdx.x, t = threadIdx.x;
    __shared__ double red4[4];
    __shared__ double mi[64];
    __shared__ float hpEs;
    int n = histpm[b * 256 + t];
    float p = (float)n * (1.0f / 65536.0f);
    double term = -(double)(p * __logf(p + 1e-8f));
    double h = blockSumD(term, red4);
    if (t == 0) hpEs = (float)h;
    __syncthreads();
    if (t < 64) mi[t] = (double)hpEs + (double)hmsE[b * CC + t] - (double)hjoint[b * CC + t];
    __syncthreads();
    if (t == 0) {
        double mxv = mi[0];
        for (int c2 = 1; c2 < 64; ++c2) if (mi[c2] > mxv) mxv = mi[c2];
        double s = 0.0;
        for (int c2 = 0; c2 < 64; ++c2) { mi[c2] = exp(mi[c2] - mxv); s += mi[c2]; }
        for (int c2 = 0; c2 < 64; ++c2) mi[c2] /= s;
    }
    __syncthreads();
    const float* srcm = fms + (size_t)b * CC * QQ;
    float* dstm = out2 + (size_t)b * CC * QQ;
    for (int e = t; e < CC * QQ; e += 256) {
        float v = srcm[e];
        float miv = (float)mi[e >> 8];
        dstm[e] = v + v * miv;
    }
}

extern "C" void kernel_launch(void* const* d_in, const int* in_sizes, int n_in,
                              void* d_out, int out_size, void* d_ws, size_t ws_size,
                              hipStream_t stream) {
    const float* fp = (const float*)d_in[0];   // [8,64,256,256]
    const float* fms = (const float*)d_in[1];  // [8,64,16,16]
    float* out = (float*)d_out;

    char* p = (char*)d_ws;
    auto alloc = [&](size_t bytes) { void* r = (void*)p; p += (bytes + 255) & ~(size_t)255; return r; };

    float* fpm      = (float*)alloc((size_t)BB * PP * 4);        // 2 MB (channel means)
    // ---- contiguous zero-init region (single hipMemsetAsync) ----
    char* zbeg = p;
    float* gtent    = (float*)alloc((size_t)BB * CC * QQ * 4);   // 512 KB
    double* pasumD  = (double*)alloc((size_t)BB * 256 * 8);      // 16 KB
    double* chsumD  = (double*)alloc((size_t)BB * CC * 8);
    double* chsumsqD= (double*)alloc((size_t)BB * CC * 8);
    unsigned* minmax= (unsigned*)alloc((size_t)BB * 2 * 4);
    int* histpm     = (int*)alloc((size_t)BB * 256 * 4);
    size_t zlen = (size_t)(p - zbeg);
    // ---- end zero region ----
    int* msn        = (int*)alloc((size_t)BB * CC * QQ * 4);     // 512 KB
    int* histms     = (int*)alloc((size_t)BB * CC * 256 * 4);    // 512 KB
    int* histp      = (int*)alloc((size_t)BB * 256 * 4);
    int* pan        = (int*)alloc((size_t)BB * QQ * 4);
    float* hmsE     = (float*)alloc((size_t)BB * CC * 4);
    float* hjoint   = (float*)alloc((size_t)BB * CC * 4);
    float* naArr    = (float*)alloc((size_t)BB * CC * 4);
    float* mssum    = (float*)alloc((size_t)BB * CC * 4);
    float* mxArr    = (float*)alloc((size_t)BB * CC * 4);
    int* idxArr     = (int*)alloc((size_t)BB * CC * 4);
    float* wsel     = (float*)alloc((size_t)BB * CC * 4);
    int* chanA      = (int*)alloc((size_t)BB * CC * 4);
    int* minkA      = (int*)alloc(256);

    float* out_relp  = out;                                      // [8,64,256,256]
    float* out_relms = out + (size_t)BB * CC * PP;               // [8,64,16,16]

    hipMemsetAsync(zbeg, 0, zlen, stream);
    k34_fused<<<4608, 256, 0, stream>>>(fp, fms, pasumD, gtent, chsumD, chsumsqD,
                                        msn, histms, hmsE, naArr, mssum);
    kC5_pa<<<8, 256, 0, stream>>>(pasumD, pan, histp);
    k86_fused<<<1024, 256, 0, stream>>>(fms, gtent, mssum, chsumD, chsumsqD, naArr,
                                        msn, pan, histms, histp, mxArr, idxArr, hjoint);
    k9_small<<<1, 512, 0, stream>>>(mxArr, idxArr, wsel, chanA, minkA);
    k10_relp<<<dim3(64, 8), 256, 0, stream>>>(fp, wsel, chanA, minkA, out_relp, fpm, minmax);
    k2a_hist<<<dim3(64, 8), 256, 0, stream>>>(fpm, minmax, histpm);
    kF_relms<<<8, 256, 0, stream>>>(histpm, fms, hmsE, hjoint, out_relms);
}